// Round 4
// baseline (294.384 us; speedup 1.0000x reference)
//
#include <hip/hip_runtime.h>
#include <hip/hip_bf16.h>

#define NN 200000
#define D 128
#define P 4096
#define R 4
#define T 3
#define K 16

__device__ __forceinline__ float bf2f(unsigned int u) {
    union { unsigned int i; float f; } c;
    c.i = u << 16;
    return c.f;
}
__device__ __forceinline__ unsigned short f2bf(float x) {  // RNE
    union { float f; unsigned int i; } c; c.f = x;
    unsigned int r = c.i + 0x7FFFu + ((c.i >> 16) & 1u);
    return (unsigned short)(r >> 16);
}
__device__ __forceinline__ float ldE(const void* p, size_t i, int f32) {
    return f32 ? ((const float*)p)[i] : bf2f(((const unsigned short*)p)[i]);
}
__device__ __forceinline__ void ld8(const void* p, size_t off, int f32, float* o) {
    if (f32) {
        const float* q = (const float*)p + off;
        float4 a = *(const float4*)q;
        float4 b = *(const float4*)(q + 4);
        o[0]=a.x; o[1]=a.y; o[2]=a.z; o[3]=a.w;
        o[4]=b.x; o[5]=b.y; o[6]=b.z; o[7]=b.w;
    } else {
        uint4 r = *(const uint4*)((const unsigned short*)p + off);
        o[0]=bf2f(r.x & 0xffffu); o[1]=bf2f(r.x >> 16);
        o[2]=bf2f(r.y & 0xffffu); o[3]=bf2f(r.y >> 16);
        o[4]=bf2f(r.z & 0xffffu); o[5]=bf2f(r.z >> 16);
        o[6]=bf2f(r.w & 0xffffu); o[7]=bf2f(r.w >> 16);
    }
}

// Kernel A: dtype sniffing (bf16 vs fp32) — validated rounds 2-3 (bf16 path, passed).
__global__ void detect_dtype(const unsigned short* __restrict__ emb, int* __restrict__ flag) {
    int tid = threadIdx.x;
    int bad = 0;
    #pragma unroll
    for (int i = 0; i < 4; ++i) {
        unsigned short u = emb[(size_t)(tid * 4 + i) * 2 * 97];
        unsigned int e = (u >> 7) & 0xFFu;
        if (e >= 147u) bad = 1;
    }
    int any_bad = __any(bad);
    if (tid == 0) *flag = any_bad ? 1 : 0;
}

// Kernel B: v_t = W_phi[t] @ zn ; u_t = W_phi[t] @ zs
__global__ void precompute_vu(const void* __restrict__ W_phi,
                              const void* __restrict__ W_zeta,
                              const int* __restrict__ flag,
                              float* __restrict__ ws_v, float* __restrict__ ws_u) {
    const int f32 = *flag;
    const int t = blockIdx.x;
    const int d = threadIdx.x;
    const size_t rb = (size_t)(t * D + d) * D;
    float av = 0.f, au = 0.f;
    for (int e = 0; e < D; e += 8) {
        float w[8], zn[8], zs[8];
        ld8(W_phi, rb + e, f32, w);
        ld8(W_zeta, e, f32, zn);
        ld8(W_zeta, D + e, f32, zs);
        #pragma unroll
        for (int q = 0; q < 8; ++q) { av += w[q] * zn[q]; au += w[q] * zs[q]; }
    }
    ws_v[t * D + d] = av;
    ws_u[t * D + d] = au;
}

// Kernel C: c[n]=emb[n].v_{t(n)}, c2[n]=emb[n].u_{t(n)}. 4 independent rows
// in flight per thread (MLP), 16 lanes per row. 3125 blocks x 64 nodes.
__global__ __launch_bounds__(256) void precompute_c(
    const void* __restrict__ emb, const int* __restrict__ types,
    const float* __restrict__ ws_v, const float* __restrict__ ws_u,
    const int* __restrict__ flag,
    float* __restrict__ c, float* __restrict__ c2)
{
    __shared__ float vsh[T * D], ush[T * D];
    const int f32 = *flag;
    const int tid = threadIdx.x;
    for (int i = tid; i < T * D; i += 256) { vsh[i] = ws_v[i]; ush[i] = ws_u[i]; }
    __syncthreads();
    const int w = tid >> 6, l = tid & 63;
    const int grp = l >> 4, ch = l & 15;
    const int nbase = blockIdx.x * 64 + w * 4 + grp;

    int   tt[4];
    float rv[4][8];
    #pragma unroll
    for (int it = 0; it < 4; ++it) {
        int n = nbase + it * 16;
        tt[it] = types[n];
        ld8(emb, (size_t)n * D + ch * 8, f32, rv[it]);
    }
    #pragma unroll
    for (int it = 0; it < 4; ++it) {
        int n = nbase + it * 16;
        const float* vp = vsh + tt[it] * D + ch * 8;
        const float* up = ush + tt[it] * D + ch * 8;
        float a = 0.f, b = 0.f;
        #pragma unroll
        for (int q = 0; q < 8; ++q) { a += rv[it][q] * vp[q]; b += rv[it][q] * up[q]; }
        #pragma unroll
        for (int off = 1; off <= 8; off <<= 1) {
            a += __shfl_xor(a, off, 64);
            b += __shfl_xor(b, off, 64);
        }
        if (ch == 0) { c[n] = a; c2[n] = b; }
    }
}

// Main fused kernel: ONE WAVE = ONE PAIR. No LDS, no __syncthreads.
__global__ __launch_bounds__(256, 4) void fused_kernel(
    const void* __restrict__ emb,               // (N,D)
    const int* __restrict__ pairs,              // (P,2)
    const int* __restrict__ nbr,                // (P,2,R,K)
    const void* __restrict__ dlt,               // (P,2,R,K)
    const void* __restrict__ W_beta_w,          // (R,D,D)
    const void* __restrict__ W_beta_b,          // (R,D)
    const float* __restrict__ c,                // (N,)
    const float* __restrict__ c2,               // (N,)
    const int* __restrict__ flag,
    void* __restrict__ out)                     // (P,D)
{
    const int f32  = *flag;
    const int tid  = threadIdx.x;
    const int wv   = tid >> 6;
    const int l    = tid & 63;
    const int p    = blockIdx.x * 4 + wv;       // wave = pair
    const int rsub = l >> 4;                    // quarter-wave: row-in-quad / d-quarter
    const int ch   = l & 15;                    // 16B chunk within row
    const int base = p * 2 * R * K;             // p*128

    // --- Preload neighbor indices (coalesced) + scores.
    int nb0 = nbr[base + l];                    // row (s=0, r=l>>4, k=l&15)
    int nb1 = nbr[base + 64 + l];               // row (s=1, ...)
    float cs0 = c2[pairs[p * 2]];
    float cs1 = c2[pairs[p * 2 + 1]];
    float dt0 = ldE(dlt, (size_t)base + l, f32);
    float dt1 = ldE(dlt, (size_t)base + 64 + l, f32);
    float e0 = (c[nb0] + cs0) * __expf(-dt0);
    float e1 = (c[nb1] + cs1) * __expf(-dt1);

    // --- Softmax over K within each 16-lane group (xor bits 0-3 stay in-group).
    float m0 = e0, m1 = e1;
    #pragma unroll
    for (int off = 1; off <= 8; off <<= 1) {
        m0 = fmaxf(m0, __shfl_xor(m0, off, 64));
        m1 = fmaxf(m1, __shfl_xor(m1, off, 64));
    }
    float a0 = __expf(e0 - m0), a1 = __expf(e1 - m1);
    float s0 = a0, s1 = a1;
    #pragma unroll
    for (int off = 1; off <= 8; off <<= 1) {
        s0 += __shfl_xor(s0, off, 64);
        s1 += __shfl_xor(s1, off, 64);
    }
    a0 *= (1.f / s0);
    a1 *= (1.f / s1);

    // --- Per r-group: gather 16 rows x 2 s with alpha weights, then beta-matvec.
    float y[8] = {0.f,0.f,0.f,0.f,0.f,0.f,0.f,0.f};
    const unsigned short* eu = (const unsigned short*)emb;
    const unsigned short* Wu = (const unsigned short*)W_beta_w;

    #pragma unroll
    for (int r = 0; r < R; ++r) {
        float acc[8] = {0.f,0.f,0.f,0.f,0.f,0.f,0.f,0.f};
        if (!f32) {
            uint4 rbv[8]; float av[8];
            #pragma unroll
            for (int i = 0; i < 8; ++i) {        // i>>2 = s, rows r*16 + (i&3)*4 + rsub
                int srcl = r * 16 + (i & 3) * 4 + rsub;
                int nb   = __shfl((i >> 2) ? nb1 : nb0, srcl, 64);
                av[i]    = __shfl((i >> 2) ? a1  : a0,  srcl, 64);
                rbv[i]   = *(const uint4*)(eu + (size_t)nb * D + ch * 8);
            }
            #pragma unroll
            for (int i = 0; i < 8; ++i) {
                float a = av[i];
                acc[0] += a * bf2f(rbv[i].x & 0xffffu); acc[1] += a * bf2f(rbv[i].x >> 16);
                acc[2] += a * bf2f(rbv[i].y & 0xffffu); acc[3] += a * bf2f(rbv[i].y >> 16);
                acc[4] += a * bf2f(rbv[i].z & 0xffffu); acc[5] += a * bf2f(rbv[i].z >> 16);
                acc[6] += a * bf2f(rbv[i].w & 0xffffu); acc[7] += a * bf2f(rbv[i].w >> 16);
            }
        } else {
            #pragma unroll
            for (int i = 0; i < 8; ++i) {
                int srcl = r * 16 + (i & 3) * 4 + rsub;
                int nb   = __shfl((i >> 2) ? nb1 : nb0, srcl, 64);
                float a  = __shfl((i >> 2) ? a1  : a0,  srcl, 64);
                float rv[8]; ld8(emb, (size_t)nb * D + ch * 8, 1, rv);
                #pragma unroll
                for (int q = 0; q < 8; ++q) acc[q] += a * rv[q];
            }
        }
        // reduce over rsub -> every lane holds g[r][ch*8+q]
        #pragma unroll
        for (int q = 0; q < 8; ++q) {
            acc[q] += __shfl_xor(acc[q], 16, 64);
            acc[q] += __shfl_xor(acc[q], 32, 64);
        }
        // y[ch*8+q] += sum_{dd} g[r][rsub*32+dd] * W[r][rsub*32+dd][ch*8+q]
        // g[r][rsub*32+dd] lives in lane (rsub*4 + dd>>3), reg (dd&7).
        #pragma unroll
        for (int dd = 0; dd < 32; ++dd) {
            float gd = __shfl(acc[dd & 7], ((l & 48) >> 2) + (dd >> 3), 64);
            size_t wo = ((size_t)(r * D + (rsub * 32 + dd))) * D + ch * 8;
            if (!f32) {
                uint4 wr = *(const uint4*)(Wu + wo);
                y[0] += gd * bf2f(wr.x & 0xffffu); y[1] += gd * bf2f(wr.x >> 16);
                y[2] += gd * bf2f(wr.y & 0xffffu); y[3] += gd * bf2f(wr.y >> 16);
                y[4] += gd * bf2f(wr.z & 0xffffu); y[5] += gd * bf2f(wr.z >> 16);
                y[6] += gd * bf2f(wr.w & 0xffffu); y[7] += gd * bf2f(wr.w >> 16);
            } else {
                float wb[8]; ld8(W_beta_w, wo, 1, wb);
                #pragma unroll
                for (int q = 0; q < 8; ++q) y[q] += gd * wb[q];
            }
        }
    }

    // --- Reduce y over rsub -> all lanes have full y[ch*8+q].
    #pragma unroll
    for (int q = 0; q < 8; ++q) {
        y[q] += __shfl_xor(y[q], 16, 64);
        y[q] += __shfl_xor(y[q], 32, 64);
    }

    // --- Bias, mean, sigmoid, store (quarter-wave 0 writes the 256B row).
    float bs[8] = {0.f,0.f,0.f,0.f,0.f,0.f,0.f,0.f};
    #pragma unroll
    for (int r = 0; r < R; ++r) {
        float bb[8]; ld8(W_beta_b, (size_t)r * D + ch * 8, f32, bb);
        #pragma unroll
        for (int q = 0; q < 8; ++q) bs[q] += bb[q];
    }
    if (rsub == 0) {
        float o[8];
        #pragma unroll
        for (int q = 0; q < 8; ++q) {
            float x = (y[q] + 2.f * bs[q]) * 0.125f;
            o[q] = 1.f / (1.f + __expf(-x));
        }
        size_t ob = (size_t)p * D + ch * 8;
        if (f32) {
            *(float4*)((float*)out + ob)     = make_float4(o[0], o[1], o[2], o[3]);
            *(float4*)((float*)out + ob + 4) = make_float4(o[4], o[5], o[6], o[7]);
        } else {
            uint4 pk;
            pk.x = (unsigned int)f2bf(o[0]) | ((unsigned int)f2bf(o[1]) << 16);
            pk.y = (unsigned int)f2bf(o[2]) | ((unsigned int)f2bf(o[3]) << 16);
            pk.z = (unsigned int)f2bf(o[4]) | ((unsigned int)f2bf(o[5]) << 16);
            pk.w = (unsigned int)f2bf(o[6]) | ((unsigned int)f2bf(o[7]) << 16);
            *(uint4*)((unsigned short*)out + ob) = pk;
        }
    }
}

extern "C" void kernel_launch(void* const* d_in, const int* in_sizes, int n_in,
                              void* d_out, int out_size, void* d_ws, size_t ws_size,
                              hipStream_t stream) {
    const void* emb    = d_in[0];
    const int*  pairs  = (const int*)d_in[1];
    const int*  types  = (const int*)d_in[2];
    const int*  nbr    = (const int*)d_in[3];
    const void* dlt    = d_in[4];
    const void* W_phi  = d_in[5];
    const void* W_zeta = d_in[6];
    const void* W_bw   = d_in[7];
    const void* W_bb   = d_in[8];

    int*   flag = (int*)d_ws;
    float* ws_v = (float*)d_ws + 64;
    float* ws_u = ws_v + T * D;
    float* c    = (float*)d_ws + 1024;
    float* c2   = c + NN;

    detect_dtype<<<dim3(1), dim3(64), 0, stream>>>((const unsigned short*)emb, flag);
    precompute_vu<<<dim3(T), dim3(D), 0, stream>>>(W_phi, W_zeta, flag, ws_v, ws_u);
    precompute_c<<<dim3(NN / 64), dim3(256), 0, stream>>>(emb, types, ws_v, ws_u, flag, c, c2);
    fused_kernel<<<dim3(P / 4), dim3(256), 0, stream>>>(emb, pairs, nbr, dlt,
                                                        W_bw, W_bb, c, c2, flag, d_out);
}

// Round 5
// 283.246 us; speedup vs baseline: 1.0393x; 1.0393x over previous
//
#include <hip/hip_runtime.h>
#include <hip/hip_bf16.h>

#define NN 200000
#define D 128
#define P 4096
#define R 4
#define T 3
#define K 16

__device__ __forceinline__ float bf2f(unsigned int u) {
    union { unsigned int i; float f; } c;
    c.i = u << 16;
    return c.f;
}
__device__ __forceinline__ unsigned short f2bf(float x) {  // RNE
    union { float f; unsigned int i; } c; c.f = x;
    unsigned int r = c.i + 0x7FFFu + ((c.i >> 16) & 1u);
    return (unsigned short)(r >> 16);
}
__device__ __forceinline__ float ldE(const void* p, size_t i, int f32) {
    return f32 ? ((const float*)p)[i] : bf2f(((const unsigned short*)p)[i]);
}
__device__ __forceinline__ void ld8(const void* p, size_t off, int f32, float* o) {
    if (f32) {
        const float* q = (const float*)p + off;
        float4 a = *(const float4*)q;
        float4 b = *(const float4*)(q + 4);
        o[0]=a.x; o[1]=a.y; o[2]=a.z; o[3]=a.w;
        o[4]=b.x; o[5]=b.y; o[6]=b.z; o[7]=b.w;
    } else {
        uint4 r = *(const uint4*)((const unsigned short*)p + off);
        o[0]=bf2f(r.x & 0xffffu); o[1]=bf2f(r.x >> 16);
        o[2]=bf2f(r.y & 0xffffu); o[3]=bf2f(r.y >> 16);
        o[4]=bf2f(r.z & 0xffffu); o[5]=bf2f(r.z >> 16);
        o[6]=bf2f(r.w & 0xffffu); o[7]=bf2f(r.w >> 16);
    }
}

// Kernel A: dtype sniffing (bf16 vs fp32) — validated rounds 2-4 (bf16 path).
__global__ void detect_dtype(const unsigned short* __restrict__ emb, int* __restrict__ flag) {
    int tid = threadIdx.x;
    int bad = 0;
    #pragma unroll
    for (int i = 0; i < 4; ++i) {
        unsigned short u = emb[(size_t)(tid * 4 + i) * 2 * 97];
        unsigned int e = (u >> 7) & 0xFFu;
        if (e >= 147u) bad = 1;
    }
    int any_bad = __any(bad);
    if (tid == 0) *flag = any_bad ? 1 : 0;
}

// Kernel B: v_t = W_phi[t] @ zn ; u_t = W_phi[t] @ zs
__global__ void precompute_vu(const void* __restrict__ W_phi,
                              const void* __restrict__ W_zeta,
                              const int* __restrict__ flag,
                              float* __restrict__ ws_v, float* __restrict__ ws_u) {
    const int f32 = *flag;
    const int t = blockIdx.x;
    const int d = threadIdx.x;
    const size_t rb = (size_t)(t * D + d) * D;
    float av = 0.f, au = 0.f;
    for (int e = 0; e < D; e += 8) {
        float w[8], zn[8], zs[8];
        ld8(W_phi, rb + e, f32, w);
        ld8(W_zeta, e, f32, zn);
        ld8(W_zeta, D + e, f32, zs);
        #pragma unroll
        for (int q = 0; q < 8; ++q) { av += w[q] * zn[q]; au += w[q] * zs[q]; }
    }
    ws_v[t * D + d] = av;
    ws_u[t * D + d] = au;
}

// Kernel 1 (hot): wave = pair. Gather rows once, score inline (dot with v_t),
// in-register softmax, alpha-weighted sum -> g[p][r][:] (bf16 scratch).
// No __syncthreads after the tiny v/u staging barrier. No beta-matvec here.
__global__ __launch_bounds__(256, 2) void gather_kernel(
    const void* __restrict__ emb,               // (N,D)
    const int* __restrict__ pairs,              // (P,2)
    const int* __restrict__ types,              // (N,)
    const int* __restrict__ nbr,                // (P,2,R,K)
    const void* __restrict__ dlt,               // (P,2,R,K)
    const float* __restrict__ ws_v,             // (T,D) fp32
    const float* __restrict__ ws_u,             // (T,D) fp32
    const int* __restrict__ flag,
    unsigned short* __restrict__ g)             // (P,R,D) bf16
{
    __shared__ __align__(16) float vsh[T * D];
    __shared__ __align__(16) float ush[T * D];
    const int f32  = *flag;
    const int tid  = threadIdx.x;
    const int wv   = tid >> 6;
    const int l    = tid & 63;
    const int p    = blockIdx.x * 4 + wv;
    const int rsub = l >> 4;                    // quarter-wave
    const int ch   = l & 15;                    // 16B chunk within a row
    const int base = p * 2 * R * K;             // p*128

    for (int i = tid; i < T * D; i += 256) { vsh[i] = ws_v[i]; ush[i] = ws_u[i]; }
    __syncthreads();

    // Coalesced per-lane loads: this lane owns rows (s=0, j=l) and (s=1, j=l).
    int nb0 = nbr[base + l];
    int nb1 = nbr[base + 64 + l];
    float dt0 = ldE(dlt, (size_t)base + l, f32);
    float dt1 = ldE(dlt, (size_t)base + 64 + l, f32);
    int t0 = types[nb0];
    int t1 = types[nb1];

    // Pair-node scores e_s = emb[pair_s] . u_{type}: quarter 0 -> s=0, quarter 1 -> s=1.
    float es01 = 0.f;
    if (l < 32) {
        int s  = rsub;                          // 0 or 1
        int ns = pairs[p * 2 + s];
        int ts = types[ns];
        float rv[8]; ld8(emb, (size_t)ns * D + ch * 8, f32, rv);
        const float* up = ush + ts * D + ch * 8;
        float a = 0.f;
        #pragma unroll
        for (int q = 0; q < 8; ++q) a += rv[q] * up[q];
        #pragma unroll
        for (int off = 1; off <= 8; off <<= 1) a += __shfl_xor(a, off, 64);
        es01 = a;
    }
    float es0 = __shfl(es01, 0, 64);
    float es1 = __shfl(es01, 16, 64);

    const unsigned short* eu = (const unsigned short*)emb;

    for (int r = 0; r < R; ++r) {
        // slot i holds row (s=i>>2, k=(i&3)*4+rsub); data chunk = ch.
        int snb[8]; float sdt[8]; int stp[8];
        #pragma unroll
        for (int i = 0; i < 8; ++i) {
            int srcl = r * 16 + (i & 3) * 4 + rsub;
            snb[i] = __shfl((i >> 2) ? nb1 : nb0, srcl, 64);
            sdt[i] = __shfl((i >> 2) ? dt1 : dt0, srcl, 64);
            stp[i] = __shfl((i >> 2) ? t1  : t0,  srcl, 64);
        }

        float en[8];
        float acc[8] = {0.f,0.f,0.f,0.f,0.f,0.f,0.f,0.f};

        if (!f32) {
            uint4 rbv[8];
            #pragma unroll
            for (int i = 0; i < 8; ++i)
                rbv[i] = *(const uint4*)(eu + (size_t)snb[i] * D + ch * 8);
            // score dots (rows stay packed in rbv)
            #pragma unroll
            for (int i = 0; i < 8; ++i) {
                const float* vp = vsh + stp[i] * D + ch * 8;
                float4 v0 = *(const float4*)vp;
                float4 v1 = *(const float4*)(vp + 4);
                float a = 0.f;
                a += bf2f(rbv[i].x & 0xffffu) * v0.x + bf2f(rbv[i].x >> 16) * v0.y;
                a += bf2f(rbv[i].y & 0xffffu) * v0.z + bf2f(rbv[i].y >> 16) * v0.w;
                a += bf2f(rbv[i].z & 0xffffu) * v1.x + bf2f(rbv[i].z >> 16) * v1.y;
                a += bf2f(rbv[i].w & 0xffffu) * v1.z + bf2f(rbv[i].w >> 16) * v1.w;
                #pragma unroll
                for (int off = 1; off <= 8; off <<= 1) a += __shfl_xor(a, off, 64);
                en[i] = a;
            }
            // softmax over the 16 rows of each (s, r) group
            float ef[8];
            #pragma unroll
            for (int i = 0; i < 8; ++i)
                ef[i] = (en[i] + ((i >> 2) ? es1 : es0)) * __expf(-sdt[i]);
            float m0 = fmaxf(fmaxf(ef[0], ef[1]), fmaxf(ef[2], ef[3]));
            float m1 = fmaxf(fmaxf(ef[4], ef[5]), fmaxf(ef[6], ef[7]));
            m0 = fmaxf(m0, __shfl_xor(m0, 16, 64)); m0 = fmaxf(m0, __shfl_xor(m0, 32, 64));
            m1 = fmaxf(m1, __shfl_xor(m1, 16, 64)); m1 = fmaxf(m1, __shfl_xor(m1, 32, 64));
            float al[8], s0 = 0.f, s1 = 0.f;
            #pragma unroll
            for (int i = 0; i < 4; ++i) { al[i] = __expf(ef[i] - m0); s0 += al[i]; }
            #pragma unroll
            for (int i = 4; i < 8; ++i) { al[i] = __expf(ef[i] - m1); s1 += al[i]; }
            s0 += __shfl_xor(s0, 16, 64); s0 += __shfl_xor(s0, 32, 64);
            s1 += __shfl_xor(s1, 16, 64); s1 += __shfl_xor(s1, 32, 64);
            float i0 = 1.f / s0, i1 = 1.f / s1;
            #pragma unroll
            for (int i = 0; i < 4; ++i) al[i] *= i0;
            #pragma unroll
            for (int i = 4; i < 8; ++i) al[i] *= i1;
            // alpha-weighted sum from the same registers
            #pragma unroll
            for (int i = 0; i < 8; ++i) {
                float a = al[i];
                acc[0] += a * bf2f(rbv[i].x & 0xffffu); acc[1] += a * bf2f(rbv[i].x >> 16);
                acc[2] += a * bf2f(rbv[i].y & 0xffffu); acc[3] += a * bf2f(rbv[i].y >> 16);
                acc[4] += a * bf2f(rbv[i].z & 0xffffu); acc[5] += a * bf2f(rbv[i].z >> 16);
                acc[6] += a * bf2f(rbv[i].w & 0xffffu); acc[7] += a * bf2f(rbv[i].w >> 16);
            }
        } else {
            // fp32 fallback: two-pass gather (second pass hits L2/L3).
            #pragma unroll
            for (int i = 0; i < 8; ++i) {
                float rv[8]; ld8(emb, (size_t)snb[i] * D + ch * 8, 1, rv);
                const float* vp = vsh + stp[i] * D + ch * 8;
                float a = 0.f;
                #pragma unroll
                for (int q = 0; q < 8; ++q) a += rv[q] * vp[q];
                #pragma unroll
                for (int off = 1; off <= 8; off <<= 1) a += __shfl_xor(a, off, 64);
                en[i] = a;
            }
            float ef[8];
            #pragma unroll
            for (int i = 0; i < 8; ++i)
                ef[i] = (en[i] + ((i >> 2) ? es1 : es0)) * __expf(-sdt[i]);
            float m0 = fmaxf(fmaxf(ef[0], ef[1]), fmaxf(ef[2], ef[3]));
            float m1 = fmaxf(fmaxf(ef[4], ef[5]), fmaxf(ef[6], ef[7]));
            m0 = fmaxf(m0, __shfl_xor(m0, 16, 64)); m0 = fmaxf(m0, __shfl_xor(m0, 32, 64));
            m1 = fmaxf(m1, __shfl_xor(m1, 16, 64)); m1 = fmaxf(m1, __shfl_xor(m1, 32, 64));
            float al[8], s0 = 0.f, s1 = 0.f;
            #pragma unroll
            for (int i = 0; i < 4; ++i) { al[i] = __expf(ef[i] - m0); s0 += al[i]; }
            #pragma unroll
            for (int i = 4; i < 8; ++i) { al[i] = __expf(ef[i] - m1); s1 += al[i]; }
            s0 += __shfl_xor(s0, 16, 64); s0 += __shfl_xor(s0, 32, 64);
            s1 += __shfl_xor(s1, 16, 64); s1 += __shfl_xor(s1, 32, 64);
            float i0 = 1.f / s0, i1 = 1.f / s1;
            #pragma unroll
            for (int i = 0; i < 4; ++i) al[i] *= i0;
            #pragma unroll
            for (int i = 4; i < 8; ++i) al[i] *= i1;
            #pragma unroll
            for (int i = 0; i < 8; ++i) {
                float rv[8]; ld8(emb, (size_t)snb[i] * D + ch * 8, 1, rv);
                #pragma unroll
                for (int q = 0; q < 8; ++q) acc[q] += al[i] * rv[q];
            }
        }

        // reduce the 32 rows split across quarter-waves
        #pragma unroll
        for (int q = 0; q < 8; ++q) {
            acc[q] += __shfl_xor(acc[q], 16, 64);
            acc[q] += __shfl_xor(acc[q], 32, 64);
        }
        if (rsub == 0) {
            uint4 pk;
            pk.x = (unsigned int)f2bf(acc[0]) | ((unsigned int)f2bf(acc[1]) << 16);
            pk.y = (unsigned int)f2bf(acc[2]) | ((unsigned int)f2bf(acc[3]) << 16);
            pk.z = (unsigned int)f2bf(acc[4]) | ((unsigned int)f2bf(acc[5]) << 16);
            pk.w = (unsigned int)f2bf(acc[6]) | ((unsigned int)f2bf(acc[7]) << 16);
            *(uint4*)(g + ((size_t)p * R + r) * D + ch * 8) = pk;
        }
    }
}

// Kernel 2: y[p][e] = sum_{rd} g[p][rd] * Wcat[rd][e] (Wcat = W_beta_w as 512x128),
// + bias, sigmoid, store. Dense, streaming, trivial.
__global__ __launch_bounds__(256, 2) void beta_gemm(
    const unsigned short* __restrict__ g,       // (P, 512) bf16
    const void* __restrict__ W_bw,              // (512,128)
    const void* __restrict__ W_bb,              // (R,D)
    const int* __restrict__ flag,
    void* __restrict__ out)                     // (P,D)
{
    __shared__ float gl[16 * 513];              // +1 pad breaks 16-way bank stride
    const int f32 = *flag;
    const int tid = threadIdx.x;
    const int pl  = tid >> 4;                   // pair within block (16)
    const int eb  = (tid & 15) * 8;             // e base
    const size_t pbase = (size_t)blockIdx.x * 16 * 512;

    // stage g -> LDS as fp32 (each thread: 4 x 8 elements, coalesced uint4)
    for (int i = tid * 8; i < 16 * 512; i += 256 * 8) {
        float v[8]; ld8(g, pbase + i, 0, v);
        int pp = i >> 9, kk = i & 511;
        #pragma unroll
        for (int q = 0; q < 8; ++q) gl[pp * 513 + kk + q] = v[q];
    }
    __syncthreads();

    float y[8] = {0.f,0.f,0.f,0.f,0.f,0.f,0.f,0.f};
    const unsigned short* Wu = (const unsigned short*)W_bw;
    if (!f32) {
        #pragma unroll 8
        for (int k = 0; k < 512; ++k) {
            float gd = gl[pl * 513 + k];
            uint4 wr = *(const uint4*)(Wu + (size_t)k * D + eb);
            y[0] += gd * bf2f(wr.x & 0xffffu); y[1] += gd * bf2f(wr.x >> 16);
            y[2] += gd * bf2f(wr.y & 0xffffu); y[3] += gd * bf2f(wr.y >> 16);
            y[4] += gd * bf2f(wr.z & 0xffffu); y[5] += gd * bf2f(wr.z >> 16);
            y[6] += gd * bf2f(wr.w & 0xffffu); y[7] += gd * bf2f(wr.w >> 16);
        }
    } else {
        #pragma unroll 4
        for (int k = 0; k < 512; ++k) {
            float gd = gl[pl * 513 + k];
            float wb[8]; ld8(W_bw, (size_t)k * D + eb, 1, wb);
            #pragma unroll
            for (int q = 0; q < 8; ++q) y[q] += gd * wb[q];
        }
    }

    float bs[8] = {0.f,0.f,0.f,0.f,0.f,0.f,0.f,0.f};
    #pragma unroll
    for (int r = 0; r < R; ++r) {
        float bb[8]; ld8(W_bb, (size_t)r * D + eb, f32, bb);
        #pragma unroll
        for (int q = 0; q < 8; ++q) bs[q] += bb[q];
    }

    int p = blockIdx.x * 16 + pl;
    size_t ob = (size_t)p * D + eb;
    float o[8];
    #pragma unroll
    for (int q = 0; q < 8; ++q) {
        float x = (y[q] + 2.f * bs[q]) * 0.125f;
        o[q] = 1.f / (1.f + __expf(-x));
    }
    if (f32) {
        *(float4*)((float*)out + ob)     = make_float4(o[0], o[1], o[2], o[3]);
        *(float4*)((float*)out + ob + 4) = make_float4(o[4], o[5], o[6], o[7]);
    } else {
        uint4 pk;
        pk.x = (unsigned int)f2bf(o[0]) | ((unsigned int)f2bf(o[1]) << 16);
        pk.y = (unsigned int)f2bf(o[2]) | ((unsigned int)f2bf(o[3]) << 16);
        pk.z = (unsigned int)f2bf(o[4]) | ((unsigned int)f2bf(o[5]) << 16);
        pk.w = (unsigned int)f2bf(o[6]) | ((unsigned int)f2bf(o[7]) << 16);
        *(uint4*)((unsigned short*)out + ob) = pk;
    }
}

extern "C" void kernel_launch(void* const* d_in, const int* in_sizes, int n_in,
                              void* d_out, int out_size, void* d_ws, size_t ws_size,
                              hipStream_t stream) {
    const void* emb    = d_in[0];
    const int*  pairs  = (const int*)d_in[1];
    const int*  types  = (const int*)d_in[2];
    const int*  nbr    = (const int*)d_in[3];
    const void* dlt    = d_in[4];
    const void* W_phi  = d_in[5];
    const void* W_zeta = d_in[6];
    const void* W_bw   = d_in[7];
    const void* W_bb   = d_in[8];

    int*   flag = (int*)d_ws;                        // bytes [0,256)
    float* ws_v = (float*)d_ws + 64;                 // 384 floats
    float* ws_u = ws_v + T * D;                      // 384 floats
    unsigned short* g = (unsigned short*)((float*)d_ws + 1024);  // P*R*D bf16 = 4 MB

    detect_dtype<<<dim3(1), dim3(64), 0, stream>>>((const unsigned short*)emb, flag);
    precompute_vu<<<dim3(T), dim3(D), 0, stream>>>(W_phi, W_zeta, flag, ws_v, ws_u);
    gather_kernel<<<dim3(P / 4), dim3(256), 0, stream>>>(emb, pairs, types, nbr, dlt,
                                                         ws_v, ws_u, flag, g);
    beta_gemm<<<dim3(P / 16), dim3(256), 0, stream>>>(g, W_bw, W_bb, flag, d_out);
}

// Round 6
// 243.985 us; speedup vs baseline: 1.2066x; 1.1609x over previous
//
#include <hip/hip_runtime.h>
#include <hip/hip_bf16.h>

#define NN 200000
#define D 128
#define P 4096
#define R 4
#define T 3
#define K 16

__device__ __forceinline__ float bf2f(unsigned int u) {
    union { unsigned int i; float f; } c;
    c.i = u << 16;
    return c.f;
}
__device__ __forceinline__ unsigned short f2bf(float x) {  // RNE
    union { float f; unsigned int i; } c; c.f = x;
    unsigned int r = c.i + 0x7FFFu + ((c.i >> 16) & 1u);
    return (unsigned short)(r >> 16);
}
__device__ __forceinline__ float ldE(const void* p, size_t i, int f32) {
    return f32 ? ((const float*)p)[i] : bf2f(((const unsigned short*)p)[i]);
}
__device__ __forceinline__ void ld8(const void* p, size_t off, int f32, float* o) {
    if (f32) {
        const float* q = (const float*)p + off;
        float4 a = *(const float4*)q;
        float4 b = *(const float4*)(q + 4);
        o[0]=a.x; o[1]=a.y; o[2]=a.z; o[3]=a.w;
        o[4]=b.x; o[5]=b.y; o[6]=b.z; o[7]=b.w;
    } else {
        uint4 r = *(const uint4*)((const unsigned short*)p + off);
        o[0]=bf2f(r.x & 0xffffu); o[1]=bf2f(r.x >> 16);
        o[2]=bf2f(r.y & 0xffffu); o[3]=bf2f(r.y >> 16);
        o[4]=bf2f(r.z & 0xffffu); o[5]=bf2f(r.z >> 16);
        o[6]=bf2f(r.w & 0xffffu); o[7]=bf2f(r.w >> 16);
    }
}

// Prep kernel: per-block dtype detection + v_t/u_t precompute. Grid = T blocks x 128.
__global__ void prep_kernel(const unsigned short* __restrict__ emb_u,
                            const void* __restrict__ W_phi,
                            const void* __restrict__ W_zeta,
                            int* __restrict__ gflag,
                            float* __restrict__ ws_v, float* __restrict__ ws_u) {
    __shared__ int sbad[2];
    const int tid = threadIdx.x;          // 0..127
    const int t   = blockIdx.x;           // 0..T-1
    // dtype sniff: even-index ushorts of bf16(N(0,1)) have small exponents;
    // of fp32 they are random mantissa bits -> uniform exponents. (validated r2-r5)
    int bad = 0;
    #pragma unroll
    for (int i = 0; i < 4; ++i) {
        unsigned short u = emb_u[(size_t)(blockIdx.x * 512 + tid * 4 + i) * 2 * 97];
        unsigned int e = (u >> 7) & 0xFFu;
        if (e >= 147u) bad = 1;
    }
    int anyb = __any(bad) ? 1 : 0;
    if ((tid & 63) == 0) sbad[tid >> 6] = anyb;
    __syncthreads();
    const int f32 = sbad[0] | sbad[1];
    if (t == 0 && tid == 0) *gflag = f32;

    const int d = tid;
    const size_t rb = (size_t)(t * D + d) * D;
    float av = 0.f, au = 0.f;
    for (int e = 0; e < D; e += 8) {
        float w[8], zn[8], zs[8];
        ld8(W_phi, rb + e, f32, w);
        ld8(W_zeta, e, f32, zn);
        ld8(W_zeta, D + e, f32, zs);
        #pragma unroll
        for (int q = 0; q < 8; ++q) { av += w[q] * zn[q]; au += w[q] * zs[q]; }
    }
    ws_v[t * D + d] = av;
    ws_u[t * D + d] = au;
}

// Fused kernel: block = 2 pairs x 2 sides; wave = (pair, side). Gather + inline
// scores + in-register softmax + alpha-sum, then beta-matvec + sigmoid epilogue.
__global__ __launch_bounds__(256, 4) void fused_all(
    const void* __restrict__ emb,               // (N,D)
    const int* __restrict__ pairs,              // (P,2)
    const int* __restrict__ types,              // (N,)
    const int* __restrict__ nbr,                // (P,2,R,K)
    const void* __restrict__ dlt,               // (P,2,R,K)
    const void* __restrict__ W_bw,              // (R,D,D)
    const void* __restrict__ W_bb,              // (R,D)
    const float* __restrict__ ws_v,             // (T,D) fp32
    const float* __restrict__ ws_u,             // (T,D) fp32
    const int* __restrict__ flag,
    void* __restrict__ out)                     // (P,D)
{
    __shared__ __align__(16) float vsh[T * D];
    __shared__ __align__(16) float ush[T * D];
    __shared__ __align__(16) float gsh[2][2][R][D];   // [pair][s][r][d] 4 KB
    __shared__ __align__(16) float ysh[2][2][D];      // [pair][half][d] 2 KB

    const int f32  = *flag;
    const int tid  = threadIdx.x;
    const int wv   = tid >> 6;
    const int l    = tid & 63;
    const int pr   = wv >> 1;                   // pair within block
    const int s    = wv & 1;                    // side
    const int p    = blockIdx.x * 2 + pr;
    const int rsub = l >> 4;                    // quarter-wave
    const int ch   = l & 15;                    // 16B (8-elem) chunk within a row
    const int base = p * 2 * R * K + s * 64;    // flat (p, s, 0, 0)

    for (int i = tid; i < T * D; i += 256) { vsh[i] = ws_v[i]; ush[i] = ws_u[i]; }
    __syncthreads();

    // Per-lane row ownership: lane l owns row j=l of side s -> (r=l>>4, k=l&15).
    const int nb  = nbr[base + l];
    const float dtv = ldE(dlt, (size_t)base + l, f32);
    const int tp  = types[nb];

    // Side score e_s = emb[pair_s] . u_{type}: lane covers elems 2l, 2l+1.
    float es;
    {
        int ns = pairs[p * 2 + s];
        int ts = types[ns];
        float a = ldE(emb, (size_t)ns * D + 2 * l,     f32) * ush[ts * D + 2 * l]
                + ldE(emb, (size_t)ns * D + 2 * l + 1, f32) * ush[ts * D + 2 * l + 1];
        #pragma unroll
        for (int off = 1; off <= 32; off <<= 1) a += __shfl_xor(a, off, 64);
        es = a;
    }

    const unsigned short* eu = (const unsigned short*)emb;

    if (!f32) {
        // ---- bf16 fast path: prefetch-pipelined r-loop ----
        int snb[4];
        uint4 cur[4], nxt[4];
        #pragma unroll
        for (int i = 0; i < 4; ++i) snb[i] = __shfl(nb, i * 4 + rsub, 64);
        #pragma unroll
        for (int i = 0; i < 4; ++i)
            cur[i] = *(const uint4*)(eu + (size_t)snb[i] * D + ch * 8);

        #pragma unroll
        for (int r = 0; r < R; ++r) {
            float sdt[4]; int stp[4];
            #pragma unroll
            for (int i = 0; i < 4; ++i) {
                int srcl = r * 16 + i * 4 + rsub;
                sdt[i] = __shfl(dtv, srcl, 64);
                stp[i] = __shfl(tp,  srcl, 64);
            }
            if (r < 3) {   // issue next r's gathers before this r's VALU phase
                #pragma unroll
                for (int i = 0; i < 4; ++i) snb[i] = __shfl(nb, (r + 1) * 16 + i * 4 + rsub, 64);
                #pragma unroll
                for (int i = 0; i < 4; ++i)
                    nxt[i] = *(const uint4*)(eu + (size_t)snb[i] * D + ch * 8);
            }
            // scores: e_n dot with v_{type}
            float ef[4];
            #pragma unroll
            for (int i = 0; i < 4; ++i) {
                const float* vp = vsh + stp[i] * D + ch * 8;
                float4 v0 = *(const float4*)vp;
                float4 v1 = *(const float4*)(vp + 4);
                float a = 0.f;
                a += bf2f(cur[i].x & 0xffffu) * v0.x + bf2f(cur[i].x >> 16) * v0.y;
                a += bf2f(cur[i].y & 0xffffu) * v0.z + bf2f(cur[i].y >> 16) * v0.w;
                a += bf2f(cur[i].z & 0xffffu) * v1.x + bf2f(cur[i].z >> 16) * v1.y;
                a += bf2f(cur[i].w & 0xffffu) * v1.z + bf2f(cur[i].w >> 16) * v1.w;
                #pragma unroll
                for (int off = 1; off <= 8; off <<= 1) a += __shfl_xor(a, off, 64);
                ef[i] = (a + es) * __expf(-sdt[i]);
            }
            // softmax over the 16 rows of (s, r)
            float m = fmaxf(fmaxf(ef[0], ef[1]), fmaxf(ef[2], ef[3]));
            m = fmaxf(m, __shfl_xor(m, 16, 64));
            m = fmaxf(m, __shfl_xor(m, 32, 64));
            float al[4], ssum = 0.f;
            #pragma unroll
            for (int i = 0; i < 4; ++i) { al[i] = __expf(ef[i] - m); ssum += al[i]; }
            ssum += __shfl_xor(ssum, 16, 64);
            ssum += __shfl_xor(ssum, 32, 64);
            float inv = 1.f / ssum;
            // alpha-weighted sum from the same registers
            float acc[8] = {0.f,0.f,0.f,0.f,0.f,0.f,0.f,0.f};
            #pragma unroll
            for (int i = 0; i < 4; ++i) {
                float a = al[i] * inv;
                acc[0] += a * bf2f(cur[i].x & 0xffffu); acc[1] += a * bf2f(cur[i].x >> 16);
                acc[2] += a * bf2f(cur[i].y & 0xffffu); acc[3] += a * bf2f(cur[i].y >> 16);
                acc[4] += a * bf2f(cur[i].z & 0xffffu); acc[5] += a * bf2f(cur[i].z >> 16);
                acc[6] += a * bf2f(cur[i].w & 0xffffu); acc[7] += a * bf2f(cur[i].w >> 16);
            }
            #pragma unroll
            for (int q = 0; q < 8; ++q) {
                acc[q] += __shfl_xor(acc[q], 16, 64);
                acc[q] += __shfl_xor(acc[q], 32, 64);
            }
            if (rsub == 0) {
                *(float4*)(&gsh[pr][s][r][ch * 8])     = make_float4(acc[0], acc[1], acc[2], acc[3]);
                *(float4*)(&gsh[pr][s][r][ch * 8 + 4]) = make_float4(acc[4], acc[5], acc[6], acc[7]);
            }
            #pragma unroll
            for (int i = 0; i < 4; ++i) cur[i] = nxt[i];
        }
    } else {
        // ---- fp32 fallback: same flow, no prefetch (register headroom) ----
        #pragma unroll
        for (int r = 0; r < R; ++r) {
            int snb[4]; float sdt[4]; int stp[4];
            #pragma unroll
            for (int i = 0; i < 4; ++i) {
                int srcl = r * 16 + i * 4 + rsub;
                snb[i] = __shfl(nb,  srcl, 64);
                sdt[i] = __shfl(dtv, srcl, 64);
                stp[i] = __shfl(tp,  srcl, 64);
            }
            float rv[4][8];
            #pragma unroll
            for (int i = 0; i < 4; ++i) ld8(emb, (size_t)snb[i] * D + ch * 8, 1, rv[i]);
            float ef[4];
            #pragma unroll
            for (int i = 0; i < 4; ++i) {
                const float* vp = vsh + stp[i] * D + ch * 8;
                float a = 0.f;
                #pragma unroll
                for (int q = 0; q < 8; ++q) a += rv[i][q] * vp[q];
                #pragma unroll
                for (int off = 1; off <= 8; off <<= 1) a += __shfl_xor(a, off, 64);
                ef[i] = (a + es) * __expf(-sdt[i]);
            }
            float m = fmaxf(fmaxf(ef[0], ef[1]), fmaxf(ef[2], ef[3]));
            m = fmaxf(m, __shfl_xor(m, 16, 64));
            m = fmaxf(m, __shfl_xor(m, 32, 64));
            float al[4], ssum = 0.f;
            #pragma unroll
            for (int i = 0; i < 4; ++i) { al[i] = __expf(ef[i] - m); ssum += al[i]; }
            ssum += __shfl_xor(ssum, 16, 64);
            ssum += __shfl_xor(ssum, 32, 64);
            float inv = 1.f / ssum;
            float acc[8] = {0.f,0.f,0.f,0.f,0.f,0.f,0.f,0.f};
            #pragma unroll
            for (int i = 0; i < 4; ++i) {
                float a = al[i] * inv;
                #pragma unroll
                for (int q = 0; q < 8; ++q) acc[q] += a * rv[i][q];
            }
            #pragma unroll
            for (int q = 0; q < 8; ++q) {
                acc[q] += __shfl_xor(acc[q], 16, 64);
                acc[q] += __shfl_xor(acc[q], 32, 64);
            }
            if (rsub == 0) {
                *(float4*)(&gsh[pr][s][r][ch * 8])     = make_float4(acc[0], acc[1], acc[2], acc[3]);
                *(float4*)(&gsh[pr][s][r][ch * 8 + 4]) = make_float4(acc[4], acc[5], acc[6], acc[7]);
            }
        }
    }
    __syncthreads();

    // ---- Beta matvec: wave (pr, s) handles r in {2s, 2s+1}.
    // y[e] += sum_d (g0[r][d]+g1[r][d]) * W[r,d,e]; lane: e = ch*8+q, d-quarter = rsub.
    float y[8] = {0.f,0.f,0.f,0.f,0.f,0.f,0.f,0.f};
    const unsigned short* Wu = (const unsigned short*)W_bw;
    #pragma unroll
    for (int rr = 0; rr < 2; ++rr) {
        const int r = s * 2 + rr;
        #pragma unroll 8
        for (int dd = 0; dd < 32; ++dd) {
            const int d = rsub * 32 + dd;
            float gd = gsh[pr][0][r][d] + gsh[pr][1][r][d];
            size_t wo = ((size_t)(r * D + d)) * D + ch * 8;
            if (!f32) {
                uint4 wr = *(const uint4*)(Wu + wo);
                y[0] += gd * bf2f(wr.x & 0xffffu); y[1] += gd * bf2f(wr.x >> 16);
                y[2] += gd * bf2f(wr.y & 0xffffu); y[3] += gd * bf2f(wr.y >> 16);
                y[4] += gd * bf2f(wr.z & 0xffffu); y[5] += gd * bf2f(wr.z >> 16);
                y[6] += gd * bf2f(wr.w & 0xffffu); y[7] += gd * bf2f(wr.w >> 16);
            } else {
                float wb[8]; ld8(W_bw, wo, 1, wb);
                #pragma unroll
                for (int q = 0; q < 8; ++q) y[q] += gd * wb[q];
            }
        }
    }
    #pragma unroll
    for (int q = 0; q < 8; ++q) {
        y[q] += __shfl_xor(y[q], 16, 64);
        y[q] += __shfl_xor(y[q], 32, 64);
    }
    if (rsub == 0) {
        *(float4*)(&ysh[pr][s][ch * 8])     = make_float4(y[0], y[1], y[2], y[3]);
        *(float4*)(&ysh[pr][s][ch * 8 + 4]) = make_float4(y[4], y[5], y[6], y[7]);
    }
    __syncthreads();

    // ---- Epilogue: waves with s==0, lanes rsub==0 (16 lanes -> 256B store).
    if (s == 0 && rsub == 0) {
        float bs[8] = {0.f,0.f,0.f,0.f,0.f,0.f,0.f,0.f};
        #pragma unroll
        for (int r = 0; r < R; ++r) {
            float bb[8]; ld8(W_bb, (size_t)r * D + ch * 8, f32, bb);
            #pragma unroll
            for (int q = 0; q < 8; ++q) bs[q] += bb[q];
        }
        float o[8];
        #pragma unroll
        for (int q = 0; q < 8; ++q) {
            int e = ch * 8 + q;
            float x = (ysh[pr][0][e] + ysh[pr][1][e] + 2.f * bs[q]) * 0.125f;
            o[q] = 1.f / (1.f + __expf(-x));
        }
        size_t ob = (size_t)p * D + ch * 8;
        if (f32) {
            *(float4*)((float*)out + ob)     = make_float4(o[0], o[1], o[2], o[3]);
            *(float4*)((float*)out + ob + 4) = make_float4(o[4], o[5], o[6], o[7]);
        } else {
            uint4 pk;
            pk.x = (unsigned int)f2bf(o[0]) | ((unsigned int)f2bf(o[1]) << 16);
            pk.y = (unsigned int)f2bf(o[2]) | ((unsigned int)f2bf(o[3]) << 16);
            pk.z = (unsigned int)f2bf(o[4]) | ((unsigned int)f2bf(o[5]) << 16);
            pk.w = (unsigned int)f2bf(o[6]) | ((unsigned int)f2bf(o[7]) << 16);
            *(uint4*)((unsigned short*)out + ob) = pk;
        }
    }
}

extern "C" void kernel_launch(void* const* d_in, const int* in_sizes, int n_in,
                              void* d_out, int out_size, void* d_ws, size_t ws_size,
                              hipStream_t stream) {
    const void* emb    = d_in[0];
    const int*  pairs  = (const int*)d_in[1];
    const int*  types  = (const int*)d_in[2];
    const int*  nbr    = (const int*)d_in[3];
    const void* dlt    = d_in[4];
    const void* W_phi  = d_in[5];
    const void* W_zeta = d_in[6];
    const void* W_bw   = d_in[7];
    const void* W_bb   = d_in[8];

    int*   flag = (int*)d_ws;                        // bytes [0,256)
    float* ws_v = (float*)d_ws + 64;                 // 384 floats
    float* ws_u = ws_v + T * D;                      // 384 floats

    prep_kernel<<<dim3(T), dim3(128), 0, stream>>>((const unsigned short*)emb,
                                                   W_phi, W_zeta, flag, ws_v, ws_u);
    fused_all<<<dim3(P / 2), dim3(256), 0, stream>>>(emb, pairs, types, nbr, dlt,
                                                     W_bw, W_bb, ws_v, ws_u, flag, d_out);
}